// Round 4
// baseline (154.390 us; speedup 1.0000x reference)
//
#include <hip/hip_runtime.h>
#include <hip/hip_bf16.h>

// BlockConvolutionLean: out = blockwise-exclusive-cumsum(X @ W^T) + b_eff
// X: [65536, 256] fp32, W: [256, 256] fp32, bias: [8] fp32, out: [65536, 256] fp32
//
// R4: kill all per-iteration global-memory dependencies in the K-loop.
//   - B fragments live in VGPRs for the whole block (tile N=64 -> 128 VGPRs),
//     loaded once from bf16 W (d_ws) before the loop. R3's K-loop serially
//     waited ~300cyc L2 B-loads + ~900cyc 1-ahead HBM stage per iteration
//     (~4200 cyc/iter measured) with too few waves to hide it.
//   - A staged via global_load_lds, quad-buffered (4x16KB), 3 chunks ahead,
//     vmcnt(8) waits: each wave keeps ~12KB of HBM reads in flight at all
//     times (8 waves/CU -> ~96KB/CU >> Little's-law ~9KB for 6.3TB/s).
//   - Stores stay contiguous via wave-private LDS transpose (R3, worked).
//   - Block mapping: the 4 ng-siblings of an mg land on the SAME XCD
//     (bx differ by 8) so the 4x logical X re-read hits that XCD's L2.

typedef short short8 __attribute__((ext_vector_type(8)));
typedef float floatx4 __attribute__((ext_vector_type(4)));
typedef unsigned short ushort4v __attribute__((ext_vector_type(4)));

typedef const __attribute__((address_space(1))) unsigned int* gas_u32p;
typedef __attribute__((address_space(3))) unsigned int* las_u32p;

// s_waitcnt with only vmcnt constrained (gfx9: vm[3:0]|[15:14], exp=7, lgkm=15)
#define WAIT_VMCNT(n) __builtin_amdgcn_s_waitcnt(0x0F70 | ((n) & 0xF) | ((((n) >> 4) & 0x3) << 14))

__device__ __forceinline__ void gl2lds16(const float* g, float* l) {
    __builtin_amdgcn_global_load_lds((gas_u32p)(const void*)g, (las_u32p)(void*)l, 16, 0, 0);
}

__device__ __forceinline__ unsigned short f2bf(float f) {
    union { float f; unsigned int u; } v;
    v.f = f;
    unsigned int u = v.u + 0x7fffu + ((v.u >> 16) & 1u);  // RNE to bf16
    return (unsigned short)(u >> 16);
}

// packed f32x8 -> bf16x8 via v_cvt_pk_bf16_f32 (RNE)
__device__ __forceinline__ short8 pack8(float4 f0, float4 f1) {
    union { __hip_bfloat162 h; unsigned int u; } c0, c1, c2, c3;
    c0.h = __float22bfloat162_rn({f0.x, f0.y});
    c1.h = __float22bfloat162_rn({f0.z, f0.w});
    c2.h = __float22bfloat162_rn({f1.x, f1.y});
    c3.h = __float22bfloat162_rn({f1.z, f1.w});
    union { short8 s; unsigned int u[4]; } r;
    r.u[0] = c0.u; r.u[1] = c1.u; r.u[2] = c2.u; r.u[3] = c3.u;
    return r.s;
}

// ---- Kernel 1: W fp32 -> bf16 into workspace ----
__global__ __launch_bounds__(256) void wconv_kernel(
    const float* __restrict__ W, unsigned short* __restrict__ Wb)
{
    const int i = (blockIdx.x * 256 + threadIdx.x) * 4;
    float4 f = *(const float4*)(W + i);
    ushort4v v;
    v[0] = f2bf(f.x); v[1] = f2bf(f.y); v[2] = f2bf(f.z); v[3] = f2bf(f.w);
    *(ushort4v*)(Wb + i) = v;
}

// ---- Kernel 2: GEMM + blockwise exclusive cumsum epilogue ----
// Block: 256 thr = 4 waves. Block tile M=128 x N=64; wave = private 32-row
// strip. B in regs (4 nt x 8 chunks x short8 = 128 VGPR), acc 2x4 floatx4.
__global__ __launch_bounds__(256) void bcl_gemm_kernel(
    const float* __restrict__ X, const unsigned short* __restrict__ Wb,
    const float* __restrict__ bias, float* __restrict__ out)
{
    __shared__ float buf[4][128 * 32];   // 4 x 16 KB A-chunk buffers

    const int tid  = threadIdx.x;
    const int lane = tid & 63;
    const int w    = tid >> 6;                     // wave 0..3
    const int bx   = blockIdx.x;
    // sibling-on-same-XCD mapping: bx = (mg>>3)*32 + ng*8 + (mg&7)
    const int mg   = ((bx >> 5) << 3) | (bx & 7); // 0..511
    const int ng   = (bx >> 3) & 3;               // 0..3 (64-col quarter)

    const int cl = lane & 15;
    const int q  = lane >> 4;

    // ---- B fragments for the whole K range, once, into registers ----
    // lane holds Wb[n = ng*64 + nt*16 + cl][k = c*32 + q*8 .. +8] (16B each)
    short8 Brg[4][8];
    {
        const unsigned short* bBase = Wb + (size_t)(ng * 64 + cl) * 256 + q * 8;
        #pragma unroll
        for (int nt = 0; nt < 4; ++nt)
            #pragma unroll
            for (int c = 0; c < 8; ++c)
                Brg[nt][c] = *(const short8*)(bBase + nt * 16 * 256 + c * 32);
    }

    // ---- A staging geometry (same proven layout as R3) ----
    // Chunk = [128 rows][32 K] fp32; wave-private 32-row slab. Per instr:
    // 8 rows x 128B full lines; source-gather swizzle: physical 16B seg p of
    // row r holds logical seg p ^ (r&7).
    const int srow = lane >> 3;
    const int sseg = (lane & 7) ^ srow;
    const float* gsrc0 = X + (size_t)(mg * 128 + w * 32 + srow) * 256 + sseg * 4;

#define STAGE(c)                                                               \
    do {                                                                       \
        const float* _g = gsrc0 + (c) * 32;                                    \
        float* _l = &buf[(c) & 3][w * 32 * 32];                                \
        _Pragma("unroll")                                                      \
        for (int _j = 0; _j < 4; ++_j)                                         \
            gl2lds16(_g + _j * 8 * 256, _l + _j * 8 * 32);                     \
    } while (0)

    floatx4 acc[2][4];
    #pragma unroll
    for (int mt = 0; mt < 2; ++mt)
        #pragma unroll
        for (int nt = 0; nt < 4; ++nt)
            acc[mt][nt] = (floatx4){0.f, 0.f, 0.f, 0.f};

    STAGE(0);
    STAGE(1);
    STAGE(2);

    #pragma unroll
    for (int c = 0; c < 8; ++c) {        // K = 256 = 8 chunks of 32
        // retire stage(c); keep stages (c+1),(c+2) in flight (8 loads)
        if (c < 6)       WAIT_VMCNT(8);
        else if (c == 6) WAIT_VMCNT(4);
        else             WAIT_VMCNT(0);
        __builtin_amdgcn_sched_barrier(0);

        float4 af[2][2];
        #pragma unroll
        for (int mt = 0; mt < 2; ++mt)
            #pragma unroll
            for (int h = 0; h < 2; ++h)
                af[mt][h] = *(const float4*)
                    &buf[c & 3][(w * 32 + mt * 16 + cl) * 32 +
                                ((((q << 1) | h) ^ (cl & 7)) << 2)];

        if (c + 3 < 8) STAGE(c + 3);     // refill 3 ahead

        short8 a0 = pack8(af[0][0], af[0][1]);
        short8 a1 = pack8(af[1][0], af[1][1]);

        #pragma unroll
        for (int nt = 0; nt < 4; ++nt) {
            acc[0][nt] = __builtin_amdgcn_mfma_f32_16x16x32_bf16(
                a0, Brg[nt][c], acc[0][nt], 0, 0, 0);
            acc[1][nt] = __builtin_amdgcn_mfma_f32_16x16x32_bf16(
                a1, Brg[nt][c], acc[1][nt], 0, 0, 0);
        }
    }
#undef STAGE

    // ---- Epilogue: cumsum + bias, transpose via wave-private LDS, stream out
    // C/D layout: col = cl, tile-row = q*4 + reg; row%8 = (q&1)*4 + reg.
    float be[4];
    {
        const int off = (q & 1) * 4;
        be[0] = bias[off + 0];
        be[1] = bias[off + 1];
        be[2] = bias[off + 2];
        be[3] = bias[off + 3];
        if (off == 0) be[0] += bias[0];   // b_eff[0] = 2*bias[0]
    }

    // wave-private 2 KB scratch inside buf[0] slab (no in-flight DMA targets
    // buf[0] after the loop: only stages 6,7 -> buf[2],buf[3] were pending)
    float* epi = &buf[0][w * 32 * 32];

    #pragma unroll
    for (int p = 0; p < 4; ++p) {        // 8-row group p of the 32-row slab
        const int mt  = p >> 1;
        const bool act = ((q >> 1) == (p & 1));
        #pragma unroll
        for (int nt = 0; nt < 4; ++nt) {
            floatx4 v = acc[mt][nt];
            float p1 = v[0];
            float p2 = p1 + v[1];
            float p3 = p2 + v[2];
            float tot = p3 + v[3];
            float below = __shfl_up(tot, 16);   // previous quad's block total
            float p0 = 0.f;
            if (q & 1) { p0 = below; p1 += below; p2 += below; p3 += below; }
            if (act) {
                float* dst = epi + (q & 1) * 4 * 64 + nt * 16 + cl;
                dst[0]   = p0 + be[0];
                dst[64]  = p1 + be[1];
                dst[128] = p2 + be[2];
                dst[192] = p3 + be[3];
            }
        }
        // read back rows, store contiguous 256B per out row (dwordx4 stream)
        #pragma unroll
        for (int k = 0; k < 2; ++k) {
            const int r   = k * 4 + (lane >> 4);   // 0..7
            const int c16 = lane & 15;
            floatx4 vv = *(const floatx4*)&epi[r * 64 + c16 * 4];
            const size_t grow = (size_t)(mg * 128 + w * 32 + p * 8 + r);
            *(floatx4*)&out[grow * 256 + ng * 64 + c16 * 4] = vv;
        }
    }
}

extern "C" void kernel_launch(void* const* d_in, const int* in_sizes, int n_in,
                              void* d_out, int out_size, void* d_ws, size_t ws_size,
                              hipStream_t stream)
{
    const float* X = (const float*)d_in[0];  // seq_vector [8*8192, 256]
    const float* W = (const float*)d_in[1];  // [256, 256]
    const float* B = (const float*)d_in[2];  // [8]
    float* out = (float*)d_out;              // [8*8192, 256]
    unsigned short* Wb = (unsigned short*)d_ws;  // 256*256 bf16 = 128 KB

    wconv_kernel<<<dim3(64), dim3(256), 0, stream>>>(W, Wb);
    bcl_gemm_kernel<<<dim3(2048), dim3(256), 0, stream>>>(X, Wb, B, out);
}

// Round 6
// 145.039 us; speedup vs baseline: 1.0645x; 1.0645x over previous
//
#include <hip/hip_runtime.h>
#include <hip/hip_bf16.h>

// BlockConvolutionLean: out = blockwise-exclusive-cumsum(X @ W^T) + b_eff
// X: [65536, 256] fp32, W: [256, 256] fp32, bias: [8] fp32, out: [65536, 256] fp32
//
// R6 = R5 with the A-ring bug fixed. R5's depth-3 ring + 3-ahead prefetch
// overwrote af[c%3] BEFORE pack8 consumed it (iters 0..4 summed chunks 3..7).
// Fix: consume (pack8) before issuing LOADA(c+3).
// R5 design rationale (unchanged):
//   - ~5000 cyc/K-iter invariant across R1-R4 -> latency convoy; vmcnt
//     retires in issue order, so any per-iter L2 load mixed into the queue
//     drains the whole stage pipeline (R3), and R4's "B in registers" was
//     silently sunk into the loop by the compiler (VGPR_Count=104 < 128
//     needed for a live Brg) recreating that convoy.
//   - A: plain dwordx4 loads, depth-3 register pipeline, the ONLY vmem in
//     the K-loop -> in-order vmcnt gives true pipelining.
//   - B: converter writes W bf16 in exact MFMA fragment order; block stages
//     32 KB linearly; ds_read_b128 lane-linear (zero conflicts). 1 barrier.
//   - LDS 40 KB + VGPR<=128 (launch_bounds 256,4) -> 4 blocks/CU = 16
//     waves/CU; ~16x32B HBM loads in flight per wave.
//   - Stores via wave-private LDS transpose (256B runs, full lines).

typedef short short8 __attribute__((ext_vector_type(8)));
typedef float floatx4 __attribute__((ext_vector_type(4)));

// s_waitcnt with only vmcnt constrained (gfx9: vm[3:0]|[15:14], exp=7, lgkm=15)
#define WAIT_VMCNT(n) __builtin_amdgcn_s_waitcnt(0x0F70 | ((n) & 0xF) | ((((n) >> 4) & 0x3) << 14))

// packed f32x8 -> bf16x8 via v_cvt_pk_bf16_f32 (RNE)
__device__ __forceinline__ short8 pack8(float4 f0, float4 f1) {
    union { __hip_bfloat162 h; unsigned int u; } c0, c1, c2, c3;
    c0.h = __float22bfloat162_rn({f0.x, f0.y});
    c1.h = __float22bfloat162_rn({f0.z, f0.w});
    c2.h = __float22bfloat162_rn({f1.x, f1.y});
    c3.h = __float22bfloat162_rn({f1.z, f1.w});
    union { short8 s; unsigned int u[4]; } r;
    r.u[0] = c0.u; r.u[1] = c1.u; r.u[2] = c2.u; r.u[3] = c3.u;
    return r.s;
}

// ---- Kernel 1: W fp32 -> bf16 in MFMA-fragment order ----
// Slot i (13 bits): cl=i&15, q=(i>>4)&3, c=(i>>6)&7, nt=(i>>9)&3, g=(i>>11)&3.
// Slot holds W[g*64 + nt*16 + cl][c*32 + q*8 .. +8] as short8.
__global__ __launch_bounds__(256) void wconv2_kernel(
    const float* __restrict__ W, unsigned short* __restrict__ Wb2)
{
    const int i  = blockIdx.x * 256 + threadIdx.x;   // 0..8191
    const int cl = i & 15;
    const int q  = (i >> 4) & 3;
    const int c  = (i >> 6) & 7;
    const int nt = (i >> 9) & 3;
    const int g  = (i >> 11) & 3;
    const float* src = W + (size_t)(g * 64 + nt * 16 + cl) * 256 + c * 32 + q * 8;
    short8 v = pack8(*(const float4*)src, *(const float4*)(src + 4));
    *(short8*)(Wb2 + (size_t)i * 8) = v;
}

// ---- Kernel 2: GEMM + blockwise exclusive cumsum epilogue ----
// Block: 256 thr = 4 waves. Block tile M=128 x N=64. Wave tile M=32 x N=64.
// Grid 2048 = 512 mg x 4 g; XCD-sibling swizzle (R4-proven: halves FETCH).
__global__ __launch_bounds__(256, 4) void bcl_gemm_kernel(
    const float* __restrict__ X, const unsigned short* __restrict__ Wb2,
    const float* __restrict__ bias, float* __restrict__ out)
{
    __shared__ unsigned short Bl[16384];   // 32 KB B fragments (linear)
    __shared__ float epis[4][512];         // 8 KB store-transpose scratch

    const int tid  = threadIdx.x;
    const int lane = tid & 63;
    const int w    = tid >> 6;                       // wave 0..3
    const int bx   = blockIdx.x;
    const int mg   = ((bx >> 5) << 3) | (bx & 7);    // 0..511
    const int g    = (bx >> 3) & 3;                  // 64-col group

    // Stage this block's B slice: pure linear 32 KB copy, one barrier.
    {
        const float4* src = (const float4*)(Wb2 + (size_t)g * 16384);
        float4* dst = (float4*)Bl;
        #pragma unroll
        for (int j = 0; j < 8; ++j)
            dst[tid * 8 + j] = src[tid * 8 + j];
    }
    __syncthreads();

    const int cl = lane & 15;
    const int q  = lane >> 4;

    // A fragment: lane holds X[m = cl][k = q*8 + j]; two float4 per (mt,c).
    const float* aBase = X + (size_t)(mg * 128 + w * 32 + cl) * 256 + q * 8;

    floatx4 acc[2][4];
    #pragma unroll
    for (int mt = 0; mt < 2; ++mt)
        #pragma unroll
        for (int nt = 0; nt < 4; ++nt)
            acc[mt][nt] = (floatx4){0.f, 0.f, 0.f, 0.f};

    float4 af[3][2][2];                    // depth-3 register A pipeline
#define LOADA(c)                                                               \
    do {                                                                       \
        _Pragma("unroll")                                                      \
        for (int _mt = 0; _mt < 2; ++_mt) {                                    \
            const float* _p = aBase + _mt * 16 * 256 + (c) * 32;               \
            af[(c) % 3][_mt][0] = *(const float4*)_p;                          \
            af[(c) % 3][_mt][1] = *(const float4*)(_p + 4);                    \
        }                                                                      \
    } while (0)

    LOADA(0); LOADA(1); LOADA(2);

    #pragma unroll
    for (int c = 0; c < 8; ++c) {          // K = 256 = 8 chunks of 32
        // A-loads are the only vmem: retire af[c], keep af[c+1],af[c+2] aloft
        if (c <= 5)      WAIT_VMCNT(8);
        else if (c == 6) WAIT_VMCNT(4);
        else             WAIT_VMCNT(0);
        __builtin_amdgcn_sched_barrier(0);

        short8 Bf[4];
        #pragma unroll
        for (int nt = 0; nt < 4; ++nt)
            Bf[nt] = *(const short8*)&Bl[(((nt * 8 + c) * 64) + lane) * 8];

        // CONSUME af[c] BEFORE the ring slot is re-targeted (R5 bug fix)
        short8 a0 = pack8(af[c % 3][0][0], af[c % 3][0][1]);
        short8 a1 = pack8(af[c % 3][1][0], af[c % 3][1][1]);

        if (c + 3 < 8) LOADA(c + 3);

        #pragma unroll
        for (int nt = 0; nt < 4; ++nt) {
            acc[0][nt] = __builtin_amdgcn_mfma_f32_16x16x32_bf16(
                a0, Bf[nt], acc[0][nt], 0, 0, 0);
            acc[1][nt] = __builtin_amdgcn_mfma_f32_16x16x32_bf16(
                a1, Bf[nt], acc[1][nt], 0, 0, 0);
        }
    }
#undef LOADA

    // ---- Epilogue: cumsum + bias, wave-private LDS transpose, 256B stores
    // C/D layout: col = cl, tile-row = q*4 + reg; row%8 = (q&1)*4 + reg.
    float be[4];
    {
        const int off = (q & 1) * 4;
        be[0] = bias[off + 0];
        be[1] = bias[off + 1];
        be[2] = bias[off + 2];
        be[3] = bias[off + 3];
        if (off == 0) be[0] += bias[0];    // b_eff[0] = 2*bias[0]
    }

    float* epi = epis[w];

    #pragma unroll
    for (int p = 0; p < 4; ++p) {          // 8-row group p of the 32-row slab
        const int mt   = p >> 1;
        const bool act = ((q >> 1) == (p & 1));
        #pragma unroll
        for (int nt = 0; nt < 4; ++nt) {
            floatx4 v = acc[mt][nt];
            float p1 = v[0];
            float p2 = p1 + v[1];
            float p3 = p2 + v[2];
            float tot = p3 + v[3];
            float below = __shfl_up(tot, 16);   // previous quad's block total
            float p0 = 0.f;
            if (q & 1) { p0 = below; p1 += below; p2 += below; p3 += below; }
            if (act) {
                float* dst = epi + (q & 1) * 4 * 64 + nt * 16 + cl;
                dst[0]   = p0 + be[0];
                dst[64]  = p1 + be[1];
                dst[128] = p2 + be[2];
                dst[192] = p3 + be[3];
            }
        }
        #pragma unroll
        for (int k = 0; k < 2; ++k) {
            const int r   = k * 4 + (lane >> 4);   // 0..7
            const int c16 = lane & 15;
            floatx4 vv = *(const floatx4*)&epi[r * 64 + c16 * 4];
            const size_t grow = (size_t)(mg * 128 + w * 32 + p * 8 + r);
            *(floatx4*)&out[grow * 256 + g * 64 + c16 * 4] = vv;
        }
    }
}

extern "C" void kernel_launch(void* const* d_in, const int* in_sizes, int n_in,
                              void* d_out, int out_size, void* d_ws, size_t ws_size,
                              hipStream_t stream)
{
    const float* X = (const float*)d_in[0];  // seq_vector [8*8192, 256]
    const float* W = (const float*)d_in[1];  // [256, 256]
    const float* B = (const float*)d_in[2];  // [8]
    float* out = (float*)d_out;              // [8*8192, 256]
    unsigned short* Wb2 = (unsigned short*)d_ws;  // 64K shorts = 128 KB

    wconv2_kernel<<<dim3(32), dim3(256), 0, stream>>>(W, Wb2);
    bcl_gemm_kernel<<<dim3(2048), dim3(256), 0, stream>>>(X, Wb2, B, out);
}